// Round 9
// baseline (1067.860 us; speedup 1.0000x reference)
//
#include <hip/hip_runtime.h>

// PointNetSetAbstraction on MI355X.
// Stages: FPS -> kNN+group+gmom -> (L1+L2 MFMA + stats2, y2 bf16) -> (L3 MFMA + max/min + stats3) -> finalize.
// Index-selection paths (FPS argmax, kNN argsort) use __fmul_rn/__fadd_rn to match numpy eval order bitwise.

#define Bc 16
#define Nn 4096
#define Ss 1024
#define Kk 32
#define COLS (Bc*Ss*Kk)   /* 524288 */
#define EPSF 1e-5f

// stats layout (floats, in ws[0..16384)) -- NO OVERLAPS:
//  S2SUM 16..528, S2SQ 528..1040, S3SUM 1040..2064, S3SQ 2064..3088, GM 3328..3456
#define S2SUM 16
#define S2SQ  528
#define S3SUM 1040
#define S3SQ  2064
#define GM    3328   /* gmom moments, 8 replicas x 16 (9 used) */

typedef unsigned long long ull;
typedef unsigned int uint32;
typedef __attribute__((ext_vector_type(8))) short bf16x8;
typedef __attribute__((ext_vector_type(4))) float f32x4;

__device__ __forceinline__ unsigned short f2bf(float f){
  uint32 u = __float_as_uint(f);
  uint32 r = (u + 0x7fffu + ((u>>16)&1u)) >> 16;
  return (unsigned short)r;
}
__device__ __forceinline__ float bf2f(unsigned short h){ return __uint_as_float(((uint32)h)<<16); }

// Full-wave (64-lane) reduces via DPP; HW-verified rounds 2/4/5/7.
__device__ __forceinline__ float dppmax_f32(float x){
  #define STEPF(ctrl,rm) { int _s=__builtin_amdgcn_update_dpp(__float_as_int(x),__float_as_int(x),(ctrl),(rm),0xf,false); x=fmaxf(x,__int_as_float(_s)); }
  STEPF(0x111,0xf) STEPF(0x112,0xf) STEPF(0x114,0xf) STEPF(0x118,0xf)
  STEPF(0x142,0xa) STEPF(0x143,0xc)
  #undef STEPF
  return __int_as_float(__builtin_amdgcn_readlane(__float_as_int(x),63));
}
__device__ __forceinline__ int dppmin_i32(int x){
  #define STEPI(ctrl,rm) { int _s=__builtin_amdgcn_update_dpp(x,x,(ctrl),(rm),0xf,false); x=min(x,_s); }
  STEPI(0x111,0xf) STEPI(0x112,0xf) STEPI(0x114,0xf) STEPI(0x118,0xf)
  STEPI(0x142,0xa) STEPI(0x143,0xc)
  #undef STEPI
  return __builtin_amdgcn_readlane(x,63);
}
// 16-lane (DPP row) suffix-sum; lane (lane&15)==15 holds the row total.
__device__ __forceinline__ float dpprowsum(float x){
  #define SSTEP(ctrl) { int _s=__builtin_amdgcn_update_dpp(__float_as_int(x),__float_as_int(x),(ctrl),0xf,0xf,false); x+=__int_as_float(_s); }
  SSTEP(0x111) SSTEP(0x112) SSTEP(0x114) SSTEP(0x118)
  #undef SSTEP
  return x;
}
// full 64-lane sum; lane 63 holds the total (old=0 so clamped lanes add 0).
__device__ __forceinline__ float dppsum64(float x){
  #define ASTEP(ctrl,rm) { int _s=__builtin_amdgcn_update_dpp(0,__float_as_int(x),(ctrl),(rm),0xf,false); x+=__int_as_float(_s); }
  ASTEP(0x111,0xf) ASTEP(0x112,0xf) ASTEP(0x114,0xf) ASTEP(0x118,0xf)
  ASTEP(0x142,0xa) ASTEP(0x143,0xc)
  #undef ASTEP
  return x;
}

// ---------------- Kernel 1: farthest point sampling (one block per batch) ----------------
// Barrier-free inner loop: parity-double-buffered LDS seqlock. Iteration it writes
// (distbits | tag<<12 | 4095-idx) to wk[it&1][wid] (tag = it+1), then polls the 4 slots of
// buffer it&1 until all tags match. Parity makes skew<=1 provably safe (a slot is rewritten
// only 2 iterations later, which requires the laggard to have advanced). Tag bits are equal
// across slots when ready, so the u64 max comparison is unaffected.
__global__ __launch_bounds__(256) void fps_kernel(const float* __restrict__ xyz,
                                                  const int* __restrict__ init_far,
                                                  float* __restrict__ new_xyz){
  __shared__ float sx[Nn*4];          // 64 KB padded [n][4]
  __shared__ ull wk[2][4];
  int b = blockIdx.x, t = threadIdx.x;
  int lane = t & 63, wid = t >> 6;
  const float* xb = xyz + (size_t)b*Nn*3;
  const float4* xb4 = (const float4*)xb;
  for(int i=t;i<Nn*3/4;i+=256){
    float4 v = xb4[i];
    int f0 = 4*i;
    sx[(f0/3)*4 + (f0%3)]       = v.x;
    sx[((f0+1)/3)*4 + ((f0+1)%3)] = v.y;
    sx[((f0+2)/3)*4 + ((f0+2)%3)] = v.z;
    sx[((f0+3)/3)*4 + ((f0+3)%3)] = v.w;
  }
  if(t<8) ((ull*)wk)[t]=0ull;         // tag field 0 = invalid (real tags start at 1)
  __syncthreads();
  const float4* sxp = (const float4*)sx;
  float px[16],py[16],pz[16],dd[16];
  #pragma unroll
  for(int j=0;j<16;j++){ int n=t+256*j; float4 p=sxp[n]; px[j]=p.x; py[j]=p.y; pz[j]=p.z; dd[j]=1e10f; }
  int far = init_far[b];
  float o0x=0.f,o0y=0.f,o0z=0.f, o1x=0.f,o1y=0.f,o1z=0.f;
  float o2x=0.f,o2y=0.f,o2z=0.f, o3x=0.f,o3y=0.f,o3z=0.f;
  for(int it=0; it<Ss; it++){
    float4 c4 = sxp[far];
    float cx=c4.x, cy=c4.y, cz=c4.z;
    if(t==(it&255)){
      if(it<256)      { o0x=cx; o0y=cy; o0z=cz; }
      else if(it<512) { o1x=cx; o1y=cy; o1z=cz; }
      else if(it<768) { o2x=cx; o2y=cy; o2z=cz; }
      else            { o3x=cx; o3y=cy; o3z=cz; }
    }
    #pragma unroll
    for(int j=0;j<16;j++){
      float dx=px[j]-cx, dy=py[j]-cy, dz=pz[j]-cz;
      float d=__fadd_rn(__fadd_rn(__fmul_rn(dx,dx),__fmul_rn(dy,dy)),__fmul_rn(dz,dz));
      dd[j]=fminf(dd[j],d);
    }
    float m0=fmaxf(fmaxf(fmaxf(dd[0],dd[1]),fmaxf(dd[2],dd[3])),fmaxf(fmaxf(dd[4],dd[5]),fmaxf(dd[6],dd[7])));
    float m1=fmaxf(fmaxf(fmaxf(dd[8],dd[9]),fmaxf(dd[10],dd[11])),fmaxf(fmaxf(dd[12],dd[13]),fmaxf(dd[14],dd[15])));
    float bd=fmaxf(m0,m1);
    float dmax = dppmax_f32(bd);
    int cj=16;
    #pragma unroll
    for(int j=15;j>=0;j--) cj = (dd[j]!=dmax) ? cj : j;
    int cand = t + (cj<<8);
    int wmin = dppmin_i32(cand);
    uint32 tag = (uint32)(it+1)<<12;
    volatile ull* wv = wk[it&1];
    if(lane==0) wk[it&1][wid] = ((ull)__float_as_uint(dmax)<<32) | tag | (uint32)(4095-wmin);
    ull g0,g1,g2,g3;
    int tries=0;
    do{
      g0=wv[0]; g1=wv[1]; g2=wv[2]; g3=wv[3];
    }while((((((uint32)g0)^tag)|(((uint32)g1)^tag)|(((uint32)g2)^tag)|(((uint32)g3)^tag)) & 0xFFFFF000u)
           && ++tries<1000000);
    ull ka = g1>g0?g1:g0, kb = g3>g2?g3:g2;
    ull kg = kb>ka?kb:ka;
    far = 4095-(int)((uint32)kg & 0xFFFu);
  }
  float* outb = new_xyz + (size_t)b*Ss*3;
  outb[t*3+0]=o0x; outb[t*3+1]=o0y; outb[t*3+2]=o0z;
  outb[(256+t)*3+0]=o1x; outb[(256+t)*3+1]=o1y; outb[(256+t)*3+2]=o1z;
  outb[(512+t)*3+0]=o2x; outb[(512+t)*3+1]=o2y; outb[(512+t)*3+2]=o2z;
  outb[(768+t)*3+0]=o3x; outb[(768+t)*3+1]=o3y; outb[(768+t)*3+2]=o3z;
}

// ---------------- Kernel 2: kNN (dual-DPP per-round min) + group + fused gmom ----------------
#define KN16(X) X(0) X(1) X(2) X(3) X(4) X(5) X(6) X(7) X(8) X(9) X(10) X(11) X(12) X(13) X(14) X(15)

__global__ __launch_bounds__(256) void knn_kernel(const float* __restrict__ xyz,
                                                  const float* __restrict__ new_xyz,
                                                  float* __restrict__ gout,
                                                  float* __restrict__ stats){
  __shared__ float nx[Ss*3];
  __shared__ float sm[9];
  int b = blockIdx.x >> 8;
  int t = threadIdx.x;
  const float4* src=(const float4*)(new_xyz + (size_t)b*Ss*3);
  float4* dst=(float4*)nx;
  for(int i=t;i<Ss*3/4;i+=256) dst[i]=src[i];
  if(t<9) sm[t]=0.f;
  __syncthreads();
  int wid=t>>6, lane=t&63;
  int s=(blockIdx.x&255)*4+wid;
  float qx=nx[s*3],qy=nx[s*3+1],qz=nx[s*3+2];
  #define KDECL(i) ull K##i;
  KN16(KDECL)
  #undef KDECL
  #define KINIT(i) { int j=lane+64*(i); \
    float dx=nx[j*3]-qx, dy=nx[j*3+1]-qy, dz=nx[j*3+2]-qz; \
    float d=__fadd_rn(__fadd_rn(__fmul_rn(dx,dx),__fmul_rn(dy,dy)),__fmul_rn(dz,dz)); \
    K##i=((ull)(__float_as_uint(d)+1u)<<32)|(uint32)(j); }
  KN16(KINIT)
  #undef KINIT
  ull last=0; int myn=0;
  for(int r=0;r<33;r++){
    ull cur=~0ull;
    #define KSCAN(i) { ull c=K##i; c=(c>last)?c:~0ull; cur=(c<cur)?c:cur; }
    KN16(KSCAN)
    #undef KSCAN
    int hs=(int)(uint32)(cur>>32);
    hs = (hs<0) ? 0x7fffffff : hs;
    int dmin = dppmin_i32(hs);
    int ci = (hs==dmin) ? (int)(uint32)cur : 0x7fffffff;
    int jmin = dppmin_i32(ci);
    last = ((ull)(uint32)dmin<<32)|(uint32)jmin;
    if(r>=1 && lane==r-1) myn=jmin;
  }
  float gx=0.f,gy=0.f,gz=0.f;
  if(lane<Kk){
    int j=myn;
    const float* p=xyz + (size_t)b*Nn*3 + (size_t)j*3;
    gx=p[0]-qx; gy=p[1]-qy; gz=p[2]-qz;
    float* go = gout + ((size_t)(b*Ss+s)*Kk + lane)*3;
    go[0]=gx; go[1]=gy; go[2]=gz;
  }
  // fused gmom: 9 moments, full-wave DPP sums, lane63 -> LDS, block -> 8-replica atomics
  float a[9]={gx,gy,gz,gx*gx,gy*gy,gz*gz,gx*gy,gx*gz,gy*gz};
  #pragma unroll
  for(int i=0;i<9;i++){
    float v=dppsum64(a[i]);
    if(lane==63) atomicAdd(&sm[i],v);
  }
  __syncthreads();
  if(t<9) atomicAdd(&stats[GM+(blockIdx.x&7)*16+t],sm[t]);
}

// ---------------- Kernel 3: layer1(BN,relu) + layer2 MFMA GEMM + fused stats2, y2 bf16 ----------------
__global__ __launch_bounds__(256) void layer12_kernel(const float* __restrict__ g,
    const float* __restrict__ W1,const float* __restrict__ b1,const float* __restrict__ g1,const float* __restrict__ be1,
    const float* __restrict__ W2,const float* __restrict__ b2,
    const float* __restrict__ stats, unsigned short* __restrict__ y2,
    float* __restrict__ statsw){
  __shared__ unsigned short x2s[128*72];   // 18 KB bf16 [col][ch pad 72]
  __shared__ unsigned short w2b[64*72];    // 9 KB bf16 [o][ch pad 72]
  __shared__ float w1s[192], b1s[64], sc1[64], sh1[64], b2s[64];
  __shared__ float rs2[64], rq2[64];
  int t=threadIdx.x;
  for(int i=t;i<4096;i+=256) w2b[(i>>6)*72+(i&63)]=f2bf(W2[i]);
  if(t<192) w1s[t]=W1[t];
  if(t<64){ b1s[t]=b1[t]; b2s[t]=b2[t]; rs2[t]=0.f; rq2[t]=0.f; }
  __syncthreads();
  if(t<64){
    const float n1=1.0f/COLS;
    float mo[9];
    #pragma unroll
    for(int i=0;i<9;i++){
      float a=0.f;
      #pragma unroll
      for(int rp=0;rp<8;rp++) a+=stats[GM+rp*16+i];
      mo[i]=a;
    }
    float ex=mo[0]*n1,ey=mo[1]*n1,ez=mo[2]*n1;
    float cxx=mo[3]*n1-ex*ex, cyy=mo[4]*n1-ey*ey, czz=mo[5]*n1-ez*ez;
    float cxy=mo[6]*n1-ex*ey, cxz=mo[7]*n1-ex*ez, cyz=mo[8]*n1-ey*ez;
    float wx=w1s[t*3],wy=w1s[t*3+1],wz=w1s[t*3+2];
    float m=wx*ex+wy*ey+wz*ez+b1s[t];
    float v=wx*wx*cxx+wy*wy*cyy+wz*wz*czz+2.f*(wx*wy*cxy+wx*wz*cxz+wy*wz*cyz);
    float sc=g1[t]*rsqrtf(v+EPSF);
    sc1[t]=sc; sh1[t]=be1[t]-m*sc;
  }
  __syncthreads();
  { // Phase A: layer1 + BN1 + relu -> x2s bf16 packed
    int col=t&127, c0=(t>>7)*32;
    size_t cg=(size_t)blockIdx.x*128+col;
    float gx=g[cg*3],gy=g[cg*3+1],gz=g[cg*3+2];
    uint32 ou[16];
    #pragma unroll
    for(int ci=0;ci<16;ci++){
      int c=c0+2*ci;
      float ya=fmaf(w1s[c*3],gx,fmaf(w1s[c*3+1],gy,fmaf(w1s[c*3+2],gz,b1s[c])));
      float va=fmaxf(fmaf(ya,sc1[c],sh1[c]),0.f);
      float yb=fmaf(w1s[c*3+3],gx,fmaf(w1s[c*3+4],gy,fmaf(w1s[c*3+5],gz,b1s[c+1])));
      float vb=fmaxf(fmaf(yb,sc1[c+1],sh1[c+1]),0.f);
      ou[ci]=(uint32)f2bf(va) | ((uint32)f2bf(vb)<<16);
    }
    uint32* xu=(uint32*)x2s;
    #pragma unroll
    for(int h=0;h<4;h++){
      ((uint4*)(xu + col*36 + (c0>>1)))[h] = make_uint4(ou[h*4],ou[h*4+1],ou[h*4+2],ou[h*4+3]);
    }
  }
  __syncthreads();
  // Phase B: MFMA. wave w -> cols w*32..+31 (2 n-tiles), 4 m-tiles, K=64 (2 steps).
  int w=t>>6, lane=t&63, quad=lane>>4, lr=lane&15;
  f32x4 acc[4][2];
  #pragma unroll
  for(int mt=0;mt<4;mt++){ acc[mt][0]=(f32x4){0.f,0.f,0.f,0.f}; acc[mt][1]=(f32x4){0.f,0.f,0.f,0.f}; }
  #pragma unroll
  for(int kt=0;kt<2;kt++){
    int ko=kt*32+quad*8;
    bf16x8 b0=*(const bf16x8*)&x2s[(w*32+lr)*72+ko];
    bf16x8 b1v=*(const bf16x8*)&x2s[(w*32+16+lr)*72+ko];
    #pragma unroll
    for(int mt=0;mt<4;mt++){
      bf16x8 a=*(const bf16x8*)&w2b[(mt*16+lr)*72+ko];
      acc[mt][0]=__builtin_amdgcn_mfma_f32_16x16x32_bf16(a,b0,acc[mt][0],0,0,0);
      acc[mt][1]=__builtin_amdgcn_mfma_f32_16x16x32_bf16(a,b1v,acc[mt][1],0,0,0);
    }
  }
  // Epilogue: bias, y2 store (bf16), fused stats2 (DPP row-sum over 16 cols, lane15 owns)
  size_t col0=(size_t)blockIdx.x*128 + w*32 + lr;
  #pragma unroll
  for(int mt=0;mt<4;mt++){
    ushort4 p0,p1;
    unsigned short* q0=(unsigned short*)&p0;
    unsigned short* q1=(unsigned short*)&p1;
    #pragma unroll
    for(int r=0;r<4;r++){
      int o=mt*16+quad*4+r;
      float bb=b2s[o];
      float v0=acc[mt][0][r]+bb, v1=acc[mt][1][r]+bb;
      q0[r]=f2bf(v0); q1[r]=f2bf(v1);
      float s_=v0+v1, sq_=fmaf(v0,v0,v1*v1);
      s_=dpprowsum(s_); sq_=dpprowsum(sq_);
      if(lr==15){ atomicAdd(&rs2[o],s_); atomicAdd(&rq2[o],sq_); }
    }
    *(ushort4*)(y2 + col0*64 + mt*16+quad*4) = p0;
    *(ushort4*)(y2 + (col0+16)*64 + mt*16+quad*4) = p1;
  }
  __syncthreads();
  if(t<64){
    int rep=blockIdx.x&7;
    atomicAdd(&statsw[S2SUM+rep*64+t],rs2[t]);
    atomicAdd(&statsw[S2SQ +rep*64+t],rq2[t]);
  }
}

// ---------------- Kernel 4: BN2+relu, layer3 MFMA GEMM, k-max/min, stats3 ----------------
__global__ __launch_bounds__(256) void layer3_kernel(const unsigned short* __restrict__ y2,
    const float* __restrict__ g2,const float* __restrict__ be2,
    const float* __restrict__ W3,const float* __restrict__ b3,
    float* __restrict__ stats, float* __restrict__ ymax, float* __restrict__ ymin){
  __shared__ unsigned short x3s[64*72];    // 9 KB bf16 [col][ch pad 72]
  __shared__ unsigned short w3b[128*72];   // 18 KB bf16 [o][ch pad 72]
  __shared__ float y3s[128*65];            // 33 KB fp32 [o][col pad]
  __shared__ float sc2[64], sh2[64], b3s[128];
  int t=threadIdx.x;
  if(t<64){
    const float n1=1.0f/COLS;
    float ssum=0.f, ssq=0.f;
    #pragma unroll
    for(int rp=0;rp<8;rp++){ ssum+=stats[S2SUM+rp*64+t]; ssq+=stats[S2SQ+rp*64+t]; }
    float m=ssum*n1;
    float v=ssq*n1-m*m;
    float sc=g2[t]*rsqrtf(v+EPSF);
    sc2[t]=sc; sh2[t]=be2[t]-m*sc;
  }
  if(t<128) b3s[t]=b3[t];
  for(int i=t;i<8192;i+=256) w3b[(i>>6)*72+(i&63)]=f2bf(W3[i]);
  __syncthreads();
  int w=t>>6, lane=t&63, quad=lane>>4, lr=lane&15;
  int q=t>>7, oo=t&127;    // Phase C roles
  float asum=0.f, asq=0.f;
  for(int tl=0; tl<4; tl++){
    int colbase=(blockIdx.x*4+tl)*64;
    { // Phase A: BN2 + relu of y2 tile -> x3s bf16 packed
      int col=t&63, c0=(t>>6)*16;
      const unsigned short* yp=y2+(size_t)(colbase+col)*64+c0;
      uint32 ou[8];
      #pragma unroll
      for(int h=0;h<2;h++){
        uint4 u=((const uint4*)yp)[h];
        uint32 ua[4]={u.x,u.y,u.z,u.w};
        #pragma unroll
        for(int e=0;e<4;e++){
          int c=c0+h*8+e*2;
          float flo=__uint_as_float(ua[e]<<16);
          float fhi=__uint_as_float(ua[e]&0xffff0000u);
          float v0=fmaxf(fmaf(flo,sc2[c],sh2[c]),0.f);
          float v1=fmaxf(fmaf(fhi,sc2[c+1],sh2[c+1]),0.f);
          ou[h*4+e]=(uint32)f2bf(v0) | ((uint32)f2bf(v1)<<16);
        }
      }
      uint32* xu=(uint32*)x3s;
      #pragma unroll
      for(int h=0;h<2;h++){
        ((uint4*)(xu + col*36 + (c0>>1)))[h] = make_uint4(ou[h*4],ou[h*4+1],ou[h*4+2],ou[h*4+3]);
      }
    }
    __syncthreads();
    // Phase B: wave w -> 16 cols (n-tile w), 8 m-tiles, K=64 (2 steps)
    f32x4 acc[8];
    #pragma unroll
    for(int mt=0;mt<8;mt++) acc[mt]=(f32x4){0.f,0.f,0.f,0.f};
    #pragma unroll
    for(int kt=0;kt<2;kt++){
      int ko=kt*32+quad*8;
      bf16x8 bfr=*(const bf16x8*)&x3s[(w*16+lr)*72+ko];
      #pragma unroll
      for(int mt=0;mt<8;mt++){
        bf16x8 afr=*(const bf16x8*)&w3b[(mt*16+lr)*72+ko];
        acc[mt]=__builtin_amdgcn_mfma_f32_16x16x32_bf16(afr,bfr,acc[mt],0,0,0);
      }
    }
    #pragma unroll
    for(int mt=0;mt<8;mt++){
      #pragma unroll
      for(int r=0;r<4;r++){
        int o=mt*16+quad*4+r;
        y3s[o*65 + w*16+lr]=acc[mt][r]+b3s[o];
      }
    }
    __syncthreads();
    { // Phase C: per-(query,channel) reduce over k=32
      float mx=-3.4e38f, mn=3.4e38f, su=0.f, sq=0.f;
      #pragma unroll
      for(int k=0;k<32;k++){
        float yv=y3s[oo*65+q*32+k];
        mx=fmaxf(mx,yv); mn=fminf(mn,yv); su+=yv; sq=fmaf(yv,yv,sq);
      }
      asum+=su; asq+=sq;
      int qg=(colbase>>5)+q;
      int bb=qg>>10, ss=qg&1023;
      ymax[((size_t)bb*128+oo)*1024+ss]=mx;
      ymin[((size_t)bb*128+oo)*1024+ss]=mn;
    }
    __syncthreads();
  }
  // combine q=0/1 partials via LDS (reuse y3s), 8-replica atomics
  if(t>=128){ y3s[t-128]=asum; y3s[128+(t-128)]=asq; }
  __syncthreads();
  if(t<128){
    asum+=y3s[t]; asq+=y3s[128+t];
    int rep=blockIdx.x&7;
    atomicAdd(&stats[S3SUM+rep*128+t],asum);
    atomicAdd(&stats[S3SQ +rep*128+t],asq);
  }
}

// ---------------- Kernel 5: finalize BN3 + relu + (max via sign of scale) ----------------
__global__ __launch_bounds__(256) void finalize_kernel(const float* __restrict__ ymax,const float* __restrict__ ymin,
    const float* __restrict__ g3,const float* __restrict__ be3,const float* __restrict__ stats,
    float* __restrict__ outp){
  int idx=blockIdx.x*256+threadIdx.x;
  int o=(idx>>10)&127;
  const float n1=1.0f/COLS;
  float ssum=0.f, ssq=0.f;
  #pragma unroll
  for(int rp=0;rp<8;rp++){ ssum+=stats[S3SUM+rp*128+o]; ssq+=stats[S3SQ+rp*128+o]; }
  float m=ssum*n1;
  float v=ssq*n1-m*m;
  float sc=g3[o]*rsqrtf(v+EPSF);
  float sh=be3[o]-m*sc;
  float val=(sc>=0.f)?ymax[idx]:ymin[idx];
  outp[idx]=fmaxf(fmaf(val,sc,sh),0.f);
}

extern "C" void kernel_launch(void* const* d_in, const int* in_sizes, int n_in,
                              void* d_out, int out_size, void* d_ws, size_t ws_size,
                              hipStream_t stream){
  const float* xyz=(const float*)d_in[0];
  const int* initf=(const int*)d_in[1];
  const float* W1=(const float*)d_in[2]; const float* b1=(const float*)d_in[3];
  const float* g1=(const float*)d_in[4]; const float* be1=(const float*)d_in[5];
  const float* W2=(const float*)d_in[6]; const float* b2=(const float*)d_in[7];
  const float* g2=(const float*)d_in[8]; const float* be2=(const float*)d_in[9];
  const float* W3=(const float*)d_in[10]; const float* b3=(const float*)d_in[11];
  const float* g3=(const float*)d_in[12]; const float* be3=(const float*)d_in[13];
  float* out=(float*)d_out;
  char* ws=(char*)d_ws;
  float* stats=(float*)(ws);
  float* gbuf=(float*)(ws+65536);
  unsigned short* y2=(unsigned short*)(ws+6361088);
  float* ymax=(float*)(ws+73469952);
  float* ymin=(float*)(ws+81858560);
  hipMemsetAsync(stats,0,16384,stream);
  fps_kernel<<<16,256,0,stream>>>(xyz,initf,out);
  knn_kernel<<<4096,256,0,stream>>>(xyz,out,gbuf,stats);
  layer12_kernel<<<4096,256,0,stream>>>(gbuf,W1,b1,g1,be1,W2,b2,stats,y2,stats);
  layer3_kernel<<<2048,256,0,stream>>>(y2,g2,be2,W3,b3,stats,ymax,ymin);
  finalize_kernel<<<8192,256,0,stream>>>(ymax,ymin,g3,be3,stats,out+49152);
}

// Round 10
// 970.003 us; speedup vs baseline: 1.1009x; 1.1009x over previous
//
#include <hip/hip_runtime.h>

// PointNetSetAbstraction on MI355X.
// Stages: FPS -> kNN+group+gmom -> (L1+L2 MFMA + stats2, y2 bf16) -> (L3 MFMA + max/min + stats3) -> finalize.
// Index-selection paths (FPS argmax, kNN argsort) use __fmul_rn/__fadd_rn to match numpy eval order bitwise.

#define Bc 16
#define Nn 4096
#define Ss 1024
#define Kk 32
#define COLS (Bc*Ss*Kk)   /* 524288 */
#define EPSF 1e-5f

// stats layout (floats, in ws[0..16384)) -- NO OVERLAPS:
//  S2SUM 16..528, S2SQ 528..1040, S3SUM 1040..2064, S3SQ 2064..3088, GM 3328..3456
#define S2SUM 16
#define S2SQ  528
#define S3SUM 1040
#define S3SQ  2064
#define GM    3328   /* gmom moments, 8 replicas x 16 (9 used) */

typedef unsigned long long ull;
typedef unsigned int uint32;
typedef __attribute__((ext_vector_type(8))) short bf16x8;
typedef __attribute__((ext_vector_type(4))) float f32x4;

__device__ __forceinline__ unsigned short f2bf(float f){
  uint32 u = __float_as_uint(f);
  uint32 r = (u + 0x7fffu + ((u>>16)&1u)) >> 16;
  return (unsigned short)r;
}
__device__ __forceinline__ float bf2f(unsigned short h){ return __uint_as_float(((uint32)h)<<16); }

// Full-wave (64-lane) reduces via DPP; HW-verified rounds 2/4/5/7.
__device__ __forceinline__ float dppmax_f32(float x){
  #define STEPF(ctrl,rm) { int _s=__builtin_amdgcn_update_dpp(__float_as_int(x),__float_as_int(x),(ctrl),(rm),0xf,false); x=fmaxf(x,__int_as_float(_s)); }
  STEPF(0x111,0xf) STEPF(0x112,0xf) STEPF(0x114,0xf) STEPF(0x118,0xf)
  STEPF(0x142,0xa) STEPF(0x143,0xc)
  #undef STEPF
  return __int_as_float(__builtin_amdgcn_readlane(__float_as_int(x),63));
}
__device__ __forceinline__ int dppmin_i32(int x){
  #define STEPI(ctrl,rm) { int _s=__builtin_amdgcn_update_dpp(x,x,(ctrl),(rm),0xf,false); x=min(x,_s); }
  STEPI(0x111,0xf) STEPI(0x112,0xf) STEPI(0x114,0xf) STEPI(0x118,0xf)
  STEPI(0x142,0xa) STEPI(0x143,0xc)
  #undef STEPI
  return __builtin_amdgcn_readlane(x,63);
}
// 16-lane (DPP row) suffix-sum; lane (lane&15)==15 holds the row total.
__device__ __forceinline__ float dpprowsum(float x){
  #define SSTEP(ctrl) { int _s=__builtin_amdgcn_update_dpp(__float_as_int(x),__float_as_int(x),(ctrl),0xf,0xf,false); x+=__int_as_float(_s); }
  SSTEP(0x111) SSTEP(0x112) SSTEP(0x114) SSTEP(0x118)
  #undef SSTEP
  return x;
}
// full 64-lane sum; lane 63 holds the total (old=0 so clamped lanes add 0).
__device__ __forceinline__ float dppsum64(float x){
  #define ASTEP(ctrl,rm) { int _s=__builtin_amdgcn_update_dpp(0,__float_as_int(x),(ctrl),(rm),0xf,false); x+=__int_as_float(_s); }
  ASTEP(0x111,0xf) ASTEP(0x112,0xf) ASTEP(0x114,0xf) ASTEP(0x118,0xf)
  ASTEP(0x142,0xa) ASTEP(0x143,0xc)
  #undef ASTEP
  return x;
}

// ---------------- Kernel 1: farthest point sampling (one block per batch) ----------------
// R7 kernel verbatim (best measured: 686-692 us). 4 waves x 16 pts/thread; per-iter
// __syncthreads (seqlock variant measured SLOWER, R9); float4-padded LDS so the
// centroid fetch is one ds_read_b128; centroids staged in registers, stored post-loop.
__global__ __launch_bounds__(256) void fps_kernel(const float* __restrict__ xyz,
                                                  const int* __restrict__ init_far,
                                                  float* __restrict__ new_xyz){
  __shared__ float sx[Nn*4];          // 64 KB padded [n][4]
  __shared__ ull wk[2][4];
  int b = blockIdx.x, t = threadIdx.x;
  int lane = t & 63, wid = t >> 6;
  const float* xb = xyz + (size_t)b*Nn*3;
  const float4* xb4 = (const float4*)xb;
  for(int i=t;i<Nn*3/4;i+=256){
    float4 v = xb4[i];
    int f0 = 4*i;
    sx[(f0/3)*4 + (f0%3)]       = v.x;
    sx[((f0+1)/3)*4 + ((f0+1)%3)] = v.y;
    sx[((f0+2)/3)*4 + ((f0+2)%3)] = v.z;
    sx[((f0+3)/3)*4 + ((f0+3)%3)] = v.w;
  }
  __syncthreads();
  const float4* sxp = (const float4*)sx;
  float px[16],py[16],pz[16],dd[16];
  #pragma unroll
  for(int j=0;j<16;j++){ int n=t+256*j; float4 p=sxp[n]; px[j]=p.x; py[j]=p.y; pz[j]=p.z; dd[j]=1e10f; }
  int far = init_far[b];
  float o0x=0.f,o0y=0.f,o0z=0.f, o1x=0.f,o1y=0.f,o1z=0.f;
  float o2x=0.f,o2y=0.f,o2z=0.f, o3x=0.f,o3y=0.f,o3z=0.f;
  for(int it=0; it<Ss; it++){
    float4 c4 = sxp[far];
    float cx=c4.x, cy=c4.y, cz=c4.z;
    if(t==(it&255)){
      if(it<256)      { o0x=cx; o0y=cy; o0z=cz; }
      else if(it<512) { o1x=cx; o1y=cy; o1z=cz; }
      else if(it<768) { o2x=cx; o2y=cy; o2z=cz; }
      else            { o3x=cx; o3y=cy; o3z=cz; }
    }
    #pragma unroll
    for(int j=0;j<16;j++){
      float dx=px[j]-cx, dy=py[j]-cy, dz=pz[j]-cz;
      float d=__fadd_rn(__fadd_rn(__fmul_rn(dx,dx),__fmul_rn(dy,dy)),__fmul_rn(dz,dz));
      dd[j]=fminf(dd[j],d);
    }
    float m0=fmaxf(fmaxf(fmaxf(dd[0],dd[1]),fmaxf(dd[2],dd[3])),fmaxf(fmaxf(dd[4],dd[5]),fmaxf(dd[6],dd[7])));
    float m1=fmaxf(fmaxf(fmaxf(dd[8],dd[9]),fmaxf(dd[10],dd[11])),fmaxf(fmaxf(dd[12],dd[13]),fmaxf(dd[14],dd[15])));
    float bd=fmaxf(m0,m1);
    float dmax = dppmax_f32(bd);
    int cj=16;
    #pragma unroll
    for(int j=15;j>=0;j--) cj = (dd[j]!=dmax) ? cj : j;
    int cand = t + (cj<<8);
    int wmin = dppmin_i32(cand);
    if(lane==0) wk[it&1][wid] = ((ull)__float_as_uint(dmax)<<32) | (uint32)(4095-wmin);
    __syncthreads();
    ull g0=wk[it&1][0], g1=wk[it&1][1], g2=wk[it&1][2], g3=wk[it&1][3];
    ull ka = g1>g0?g1:g0, kb = g3>g2?g3:g2;
    ull kg = kb>ka?kb:ka;
    far = 4095-(int)(uint32)(kg&0xffffffffu);
  }
  float* outb = new_xyz + (size_t)b*Ss*3;
  outb[t*3+0]=o0x; outb[t*3+1]=o0y; outb[t*3+2]=o0z;
  outb[(256+t)*3+0]=o1x; outb[(256+t)*3+1]=o1y; outb[(256+t)*3+2]=o1z;
  outb[(512+t)*3+0]=o2x; outb[(512+t)*3+1]=o2y; outb[(512+t)*3+2]=o2z;
  outb[(768+t)*3+0]=o3x; outb[(768+t)*3+1]=o3y; outb[(768+t)*3+2]=o3z;
}

// ---------------- Kernel 2: kNN (dual-DPP per-round min) + group + fused gmom ----------------
#define KN16(X) X(0) X(1) X(2) X(3) X(4) X(5) X(6) X(7) X(8) X(9) X(10) X(11) X(12) X(13) X(14) X(15)

__global__ __launch_bounds__(256) void knn_kernel(const float* __restrict__ xyz,
                                                  const float* __restrict__ new_xyz,
                                                  float* __restrict__ gout,
                                                  float* __restrict__ stats){
  __shared__ float nx[Ss*3];
  __shared__ float sm[9];
  int b = blockIdx.x >> 8;
  int t = threadIdx.x;
  const float4* src=(const float4*)(new_xyz + (size_t)b*Ss*3);
  float4* dst=(float4*)nx;
  for(int i=t;i<Ss*3/4;i+=256) dst[i]=src[i];
  if(t<9) sm[t]=0.f;
  __syncthreads();
  int wid=t>>6, lane=t&63;
  int s=(blockIdx.x&255)*4+wid;
  float qx=nx[s*3],qy=nx[s*3+1],qz=nx[s*3+2];
  #define KDECL(i) ull K##i;
  KN16(KDECL)
  #undef KDECL
  #define KINIT(i) { int j=lane+64*(i); \
    float dx=nx[j*3]-qx, dy=nx[j*3+1]-qy, dz=nx[j*3+2]-qz; \
    float d=__fadd_rn(__fadd_rn(__fmul_rn(dx,dx),__fmul_rn(dy,dy)),__fmul_rn(dz,dz)); \
    K##i=((ull)(__float_as_uint(d)+1u)<<32)|(uint32)(j); }
  KN16(KINIT)
  #undef KINIT
  ull last=0; int myn=0;
  for(int r=0;r<33;r++){
    ull cur=~0ull;
    #define KSCAN(i) { ull c=K##i; c=(c>last)?c:~0ull; cur=(c<cur)?c:cur; }
    KN16(KSCAN)
    #undef KSCAN
    int hs=(int)(uint32)(cur>>32);
    hs = (hs<0) ? 0x7fffffff : hs;
    int dmin = dppmin_i32(hs);
    int ci = (hs==dmin) ? (int)(uint32)cur : 0x7fffffff;
    int jmin = dppmin_i32(ci);
    last = ((ull)(uint32)dmin<<32)|(uint32)jmin;
    if(r>=1 && lane==r-1) myn=jmin;
  }
  float gx=0.f,gy=0.f,gz=0.f;
  if(lane<Kk){
    int j=myn;
    const float* p=xyz + (size_t)b*Nn*3 + (size_t)j*3;
    gx=p[0]-qx; gy=p[1]-qy; gz=p[2]-qz;
    float* go = gout + ((size_t)(b*Ss+s)*Kk + lane)*3;
    go[0]=gx; go[1]=gy; go[2]=gz;
  }
  // fused gmom: 9 moments, full-wave DPP sums, lane63 -> LDS, block -> 8-replica atomics
  float a[9]={gx,gy,gz,gx*gx,gy*gy,gz*gz,gx*gy,gx*gz,gy*gz};
  #pragma unroll
  for(int i=0;i<9;i++){
    float v=dppsum64(a[i]);
    if(lane==63) atomicAdd(&sm[i],v);
  }
  __syncthreads();
  if(t<9) atomicAdd(&stats[GM+(blockIdx.x&7)*16+t],sm[t]);
}

// ---------------- Kernel 3: layer1(BN,relu) + layer2 MFMA GEMM + fused stats2, y2 bf16 ----------------
__global__ __launch_bounds__(256) void layer12_kernel(const float* __restrict__ g,
    const float* __restrict__ W1,const float* __restrict__ b1,const float* __restrict__ g1,const float* __restrict__ be1,
    const float* __restrict__ W2,const float* __restrict__ b2,
    const float* __restrict__ stats, unsigned short* __restrict__ y2,
    float* __restrict__ statsw){
  __shared__ unsigned short x2s[128*72];   // 18 KB bf16 [col][ch pad 72]
  __shared__ unsigned short w2b[64*72];    // 9 KB bf16 [o][ch pad 72]
  __shared__ float w1s[192], b1s[64], sc1[64], sh1[64], b2s[64];
  __shared__ float rs2[64], rq2[64];
  int t=threadIdx.x;
  for(int i=t;i<4096;i+=256) w2b[(i>>6)*72+(i&63)]=f2bf(W2[i]);
  if(t<192) w1s[t]=W1[t];
  if(t<64){ b1s[t]=b1[t]; b2s[t]=b2[t]; rs2[t]=0.f; rq2[t]=0.f; }
  __syncthreads();
  if(t<64){
    const float n1=1.0f/COLS;
    float mo[9];
    #pragma unroll
    for(int i=0;i<9;i++){
      float a=0.f;
      #pragma unroll
      for(int rp=0;rp<8;rp++) a+=stats[GM+rp*16+i];
      mo[i]=a;
    }
    float ex=mo[0]*n1,ey=mo[1]*n1,ez=mo[2]*n1;
    float cxx=mo[3]*n1-ex*ex, cyy=mo[4]*n1-ey*ey, czz=mo[5]*n1-ez*ez;
    float cxy=mo[6]*n1-ex*ey, cxz=mo[7]*n1-ex*ez, cyz=mo[8]*n1-ey*ez;
    float wx=w1s[t*3],wy=w1s[t*3+1],wz=w1s[t*3+2];
    float m=wx*ex+wy*ey+wz*ez+b1s[t];
    float v=wx*wx*cxx+wy*wy*cyy+wz*wz*czz+2.f*(wx*wy*cxy+wx*wz*cxz+wy*wz*cyz);
    float sc=g1[t]*rsqrtf(v+EPSF);
    sc1[t]=sc; sh1[t]=be1[t]-m*sc;
  }
  __syncthreads();
  { // Phase A: layer1 + BN1 + relu -> x2s bf16 packed
    int col=t&127, c0=(t>>7)*32;
    size_t cg=(size_t)blockIdx.x*128+col;
    float gx=g[cg*3],gy=g[cg*3+1],gz=g[cg*3+2];
    uint32 ou[16];
    #pragma unroll
    for(int ci=0;ci<16;ci++){
      int c=c0+2*ci;
      float ya=fmaf(w1s[c*3],gx,fmaf(w1s[c*3+1],gy,fmaf(w1s[c*3+2],gz,b1s[c])));
      float va=fmaxf(fmaf(ya,sc1[c],sh1[c]),0.f);
      float yb=fmaf(w1s[c*3+3],gx,fmaf(w1s[c*3+4],gy,fmaf(w1s[c*3+5],gz,b1s[c+1])));
      float vb=fmaxf(fmaf(yb,sc1[c+1],sh1[c+1]),0.f);
      ou[ci]=(uint32)f2bf(va) | ((uint32)f2bf(vb)<<16);
    }
    uint32* xu=(uint32*)x2s;
    #pragma unroll
    for(int h=0;h<4;h++){
      ((uint4*)(xu + col*36 + (c0>>1)))[h] = make_uint4(ou[h*4],ou[h*4+1],ou[h*4+2],ou[h*4+3]);
    }
  }
  __syncthreads();
  // Phase B: MFMA. wave w -> cols w*32..+31 (2 n-tiles), 4 m-tiles, K=64 (2 steps).
  int w=t>>6, lane=t&63, quad=lane>>4, lr=lane&15;
  f32x4 acc[4][2];
  #pragma unroll
  for(int mt=0;mt<4;mt++){ acc[mt][0]=(f32x4){0.f,0.f,0.f,0.f}; acc[mt][1]=(f32x4){0.f,0.f,0.f,0.f}; }
  #pragma unroll
  for(int kt=0;kt<2;kt++){
    int ko=kt*32+quad*8;
    bf16x8 b0=*(const bf16x8*)&x2s[(w*32+lr)*72+ko];
    bf16x8 b1v=*(const bf16x8*)&x2s[(w*32+16+lr)*72+ko];
    #pragma unroll
    for(int mt=0;mt<4;mt++){
      bf16x8 a=*(const bf16x8*)&w2b[(mt*16+lr)*72+ko];
      acc[mt][0]=__builtin_amdgcn_mfma_f32_16x16x32_bf16(a,b0,acc[mt][0],0,0,0);
      acc[mt][1]=__builtin_amdgcn_mfma_f32_16x16x32_bf16(a,b1v,acc[mt][1],0,0,0);
    }
  }
  // Epilogue: bias, y2 store (bf16), fused stats2 (DPP row-sum over 16 cols, lane15 owns)
  size_t col0=(size_t)blockIdx.x*128 + w*32 + lr;
  #pragma unroll
  for(int mt=0;mt<4;mt++){
    ushort4 p0,p1;
    unsigned short* q0=(unsigned short*)&p0;
    unsigned short* q1=(unsigned short*)&p1;
    #pragma unroll
    for(int r=0;r<4;r++){
      int o=mt*16+quad*4+r;
      float bb=b2s[o];
      float v0=acc[mt][0][r]+bb, v1=acc[mt][1][r]+bb;
      q0[r]=f2bf(v0); q1[r]=f2bf(v1);
      float s_=v0+v1, sq_=fmaf(v0,v0,v1*v1);
      s_=dpprowsum(s_); sq_=dpprowsum(sq_);
      if(lr==15){ atomicAdd(&rs2[o],s_); atomicAdd(&rq2[o],sq_); }
    }
    *(ushort4*)(y2 + col0*64 + mt*16+quad*4) = p0;
    *(ushort4*)(y2 + (col0+16)*64 + mt*16+quad*4) = p1;
  }
  __syncthreads();
  if(t<64){
    int rep=blockIdx.x&7;
    atomicAdd(&statsw[S2SUM+rep*64+t],rs2[t]);
    atomicAdd(&statsw[S2SQ +rep*64+t],rq2[t]);
  }
}

// ---------------- Kernel 4: BN2+relu, layer3 MFMA GEMM, k-max/min, stats3 ----------------
__global__ __launch_bounds__(256) void layer3_kernel(const unsigned short* __restrict__ y2,
    const float* __restrict__ g2,const float* __restrict__ be2,
    const float* __restrict__ W3,const float* __restrict__ b3,
    float* __restrict__ stats, float* __restrict__ ymax, float* __restrict__ ymin){
  __shared__ unsigned short x3s[64*72];    // 9 KB bf16 [col][ch pad 72]
  __shared__ unsigned short w3b[128*72];   // 18 KB bf16 [o][ch pad 72]
  __shared__ float y3s[128*65];            // 33 KB fp32 [o][col pad]
  __shared__ float sc2[64], sh2[64], b3s[128];
  int t=threadIdx.x;
  if(t<64){
    const float n1=1.0f/COLS;
    float ssum=0.f, ssq=0.f;
    #pragma unroll
    for(int rp=0;rp<8;rp++){ ssum+=stats[S2SUM+rp*64+t]; ssq+=stats[S2SQ+rp*64+t]; }
    float m=ssum*n1;
    float v=ssq*n1-m*m;
    float sc=g2[t]*rsqrtf(v+EPSF);
    sc2[t]=sc; sh2[t]=be2[t]-m*sc;
  }
  if(t<128) b3s[t]=b3[t];
  for(int i=t;i<8192;i+=256) w3b[(i>>6)*72+(i&63)]=f2bf(W3[i]);
  __syncthreads();
  int w=t>>6, lane=t&63, quad=lane>>4, lr=lane&15;
  int q=t>>7, oo=t&127;    // Phase C roles
  float asum=0.f, asq=0.f;
  for(int tl=0; tl<4; tl++){
    int colbase=(blockIdx.x*4+tl)*64;
    { // Phase A: BN2 + relu of y2 tile -> x3s bf16 packed
      int col=t&63, c0=(t>>6)*16;
      const unsigned short* yp=y2+(size_t)(colbase+col)*64+c0;
      uint32 ou[8];
      #pragma unroll
      for(int h=0;h<2;h++){
        uint4 u=((const uint4*)yp)[h];
        uint32 ua[4]={u.x,u.y,u.z,u.w};
        #pragma unroll
        for(int e=0;e<4;e++){
          int c=c0+h*8+e*2;
          float flo=__uint_as_float(ua[e]<<16);
          float fhi=__uint_as_float(ua[e]&0xffff0000u);
          float v0=fmaxf(fmaf(flo,sc2[c],sh2[c]),0.f);
          float v1=fmaxf(fmaf(fhi,sc2[c+1],sh2[c+1]),0.f);
          ou[h*4+e]=(uint32)f2bf(v0) | ((uint32)f2bf(v1)<<16);
        }
      }
      uint32* xu=(uint32*)x3s;
      #pragma unroll
      for(int h=0;h<2;h++){
        ((uint4*)(xu + col*36 + (c0>>1)))[h] = make_uint4(ou[h*4],ou[h*4+1],ou[h*4+2],ou[h*4+3]);
      }
    }
    __syncthreads();
    // Phase B: wave w -> 16 cols (n-tile w), 8 m-tiles, K=64 (2 steps)
    f32x4 acc[8];
    #pragma unroll
    for(int mt=0;mt<8;mt++) acc[mt]=(f32x4){0.f,0.f,0.f,0.f};
    #pragma unroll
    for(int kt=0;kt<2;kt++){
      int ko=kt*32+quad*8;
      bf16x8 bfr=*(const bf16x8*)&x3s[(w*16+lr)*72+ko];
      #pragma unroll
      for(int mt=0;mt<8;mt++){
        bf16x8 afr=*(const bf16x8*)&w3b[(mt*16+lr)*72+ko];
        acc[mt]=__builtin_amdgcn_mfma_f32_16x16x32_bf16(afr,bfr,acc[mt],0,0,0);
      }
    }
    #pragma unroll
    for(int mt=0;mt<8;mt++){
      #pragma unroll
      for(int r=0;r<4;r++){
        int o=mt*16+quad*4+r;
        y3s[o*65 + w*16+lr]=acc[mt][r]+b3s[o];
      }
    }
    __syncthreads();
    { // Phase C: per-(query,channel) reduce over k=32
      float mx=-3.4e38f, mn=3.4e38f, su=0.f, sq=0.f;
      #pragma unroll
      for(int k=0;k<32;k++){
        float yv=y3s[oo*65+q*32+k];
        mx=fmaxf(mx,yv); mn=fminf(mn,yv); su+=yv; sq=fmaf(yv,yv,sq);
      }
      asum+=su; asq+=sq;
      int qg=(colbase>>5)+q;
      int bb=qg>>10, ss=qg&1023;
      ymax[((size_t)bb*128+oo)*1024+ss]=mx;
      ymin[((size_t)bb*128+oo)*1024+ss]=mn;
    }
    __syncthreads();
  }
  // combine q=0/1 partials via LDS (reuse y3s), 8-replica atomics
  if(t>=128){ y3s[t-128]=asum; y3s[128+(t-128)]=asq; }
  __syncthreads();
  if(t<128){
    asum+=y3s[t]; asq+=y3s[128+t];
    int rep=blockIdx.x&7;
    atomicAdd(&stats[S3SUM+rep*128+t],asum);
    atomicAdd(&stats[S3SQ +rep*128+t],asq);
  }
}

// ---------------- Kernel 5: finalize BN3 + relu + (max via sign of scale) ----------------
__global__ __launch_bounds__(256) void finalize_kernel(const float* __restrict__ ymax,const float* __restrict__ ymin,
    const float* __restrict__ g3,const float* __restrict__ be3,const float* __restrict__ stats,
    float* __restrict__ outp){
  int idx=blockIdx.x*256+threadIdx.x;
  int o=(idx>>10)&127;
  const float n1=1.0f/COLS;
  float ssum=0.f, ssq=0.f;
  #pragma unroll
  for(int rp=0;rp<8;rp++){ ssum+=stats[S3SUM+rp*128+o]; ssq+=stats[S3SQ+rp*128+o]; }
  float m=ssum*n1;
  float v=ssq*n1-m*m;
  float sc=g3[o]*rsqrtf(v+EPSF);
  float sh=be3[o]-m*sc;
  float val=(sc>=0.f)?ymax[idx]:ymin[idx];
  outp[idx]=fmaxf(fmaf(val,sc,sh),0.f);
}

extern "C" void kernel_launch(void* const* d_in, const int* in_sizes, int n_in,
                              void* d_out, int out_size, void* d_ws, size_t ws_size,
                              hipStream_t stream){
  const float* xyz=(const float*)d_in[0];
  const int* initf=(const int*)d_in[1];
  const float* W1=(const float*)d_in[2]; const float* b1=(const float*)d_in[3];
  const float* g1=(const float*)d_in[4]; const float* be1=(const float*)d_in[5];
  const float* W2=(const float*)d_in[6]; const float* b2=(const float*)d_in[7];
  const float* g2=(const float*)d_in[8]; const float* be2=(const float*)d_in[9];
  const float* W3=(const float*)d_in[10]; const float* b3=(const float*)d_in[11];
  const float* g3=(const float*)d_in[12]; const float* be3=(const float*)d_in[13];
  float* out=(float*)d_out;
  char* ws=(char*)d_ws;
  float* stats=(float*)(ws);
  float* gbuf=(float*)(ws+65536);
  unsigned short* y2=(unsigned short*)(ws+6361088);
  float* ymax=(float*)(ws+73469952);
  float* ymin=(float*)(ws+81858560);
  hipMemsetAsync(stats,0,16384,stream);
  fps_kernel<<<16,256,0,stream>>>(xyz,initf,out);
  knn_kernel<<<4096,256,0,stream>>>(xyz,out,gbuf,stats);
  layer12_kernel<<<4096,256,0,stream>>>(gbuf,W1,b1,g1,be1,W2,b2,stats,y2,stats);
  layer3_kernel<<<2048,256,0,stream>>>(y2,g2,be2,W3,b3,stats,ymax,ymin);
  finalize_kernel<<<8192,256,0,stream>>>(ymax,ymin,g3,be3,stats,out+49152);
}